// Round 1
// baseline (889.133 us; speedup 1.0000x reference)
//
#include <hip/hip_runtime.h>
#include <stdint.h>
#include <stddef.h>

#define TOK   16384      // B*S
#define DDIM  1024
#define NEXP  8
#define BMT   128        // expert gemm row tile (padding quantum)
#define RB_MAX 136       // ceil((TOK + NEXP*BMT)/BMT) upper bound

typedef __bf16 bf16x8 __attribute__((ext_vector_type(8)));
typedef float  f32x4  __attribute__((ext_vector_type(4)));

__device__ __forceinline__ unsigned short f2bf(float f) {
    unsigned int u = __float_as_uint(f);
    u += 0x7fff + ((u >> 16) & 1);          // round-to-nearest-even
    return (unsigned short)(u >> 16);
}

__device__ __forceinline__ void gload_lds16(const void* g, void* l) {
    __builtin_amdgcn_global_load_lds(
        (const __attribute__((address_space(1))) unsigned int*)g,
        (__attribute__((address_space(3))) unsigned int*)l, 16, 0, 0);
}

// ---------------------------------------------------------------------------
// K6: We[e][k][n] fp32 -> WeT[e][n][k] bf16  (transpose so B operand is
// k-contiguous for MFMA fragment ds_read_b128)
// ---------------------------------------------------------------------------
__global__ __launch_bounds__(256) void transpose_we(
    const float* __restrict__ We, unsigned short* __restrict__ WeT)
{
    __shared__ float tile[32][33];
    const int e  = blockIdx.z;
    const int k0 = blockIdx.x * 32;
    const int n0 = blockIdx.y * 32;
    const int tx = threadIdx.x;   // 0..31
    const int ty = threadIdx.y;   // 0..7
    const float* src = We + (size_t)e * DDIM * DDIM;
    unsigned short* dst = WeT + (size_t)e * DDIM * DDIM;
#pragma unroll
    for (int r = 0; r < 4; r++)
        tile[ty + r * 8][tx] = src[(size_t)(k0 + ty + r * 8) * DDIM + n0 + tx];
    __syncthreads();
#pragma unroll
    for (int r = 0; r < 4; r++)
        dst[(size_t)(n0 + ty + r * 8) * DDIM + k0 + tx] = f2bf(tile[tx][ty + r * 8]);
}

// ---------------------------------------------------------------------------
// K1: fp32 gating GEMM  logits[16384,1024] = x @ Wg + bg
// 128x128 block tile, BK=16, 256 threads, 8x8 per-thread micro-tile.
// fp32 on vector ALU so the argmax matches numpy bit-for-bit (bf16 logits
// would flip ~300 token argmaxes -> fail).
// ---------------------------------------------------------------------------
__global__ __launch_bounds__(256) void gating_gemm(
    const float* __restrict__ x, const float* __restrict__ Wg,
    const float* __restrict__ bg, float* __restrict__ logits)
{
    __shared__ float As[16][128];   // As[k][m] (A transposed in LDS)
    __shared__ float Bs[16][128];   // Bs[k][n]
    const int tid = threadIdx.x;
    const int m0 = blockIdx.x * 128;
    const int n0 = blockIdx.y * 128;
    const int tx = tid & 15;        // 16 col groups of 8
    const int ty = tid >> 4;        // 16 row groups of 8

    float acc[8][8];
#pragma unroll
    for (int i = 0; i < 8; i++)
#pragma unroll
        for (int j = 0; j < 8; j++) acc[i][j] = 0.f;

    const int ar = tid >> 1;            // 0..127 : A row
    const int akk = (tid & 1) * 8;      // 0 or 8 : A k offset
    const int bk = tid >> 4;            // 0..15  : B k row
    const int bc = (tid & 15) * 8;      // col offset

    for (int k0 = 0; k0 < DDIM; k0 += 16) {
        float4 a0 = *(const float4*)&x[(size_t)(m0 + ar) * DDIM + k0 + akk];
        float4 a1 = *(const float4*)&x[(size_t)(m0 + ar) * DDIM + k0 + akk + 4];
        float4 b0 = *(const float4*)&Wg[(size_t)(k0 + bk) * DDIM + n0 + bc];
        float4 b1 = *(const float4*)&Wg[(size_t)(k0 + bk) * DDIM + n0 + bc + 4];
        As[akk + 0][ar] = a0.x; As[akk + 1][ar] = a0.y;
        As[akk + 2][ar] = a0.z; As[akk + 3][ar] = a0.w;
        As[akk + 4][ar] = a1.x; As[akk + 5][ar] = a1.y;
        As[akk + 6][ar] = a1.z; As[akk + 7][ar] = a1.w;
        *(float4*)&Bs[bk][bc] = b0;
        *(float4*)&Bs[bk][bc + 4] = b1;
        __syncthreads();
#pragma unroll
        for (int k = 0; k < 16; k++) {
            float a[8], b[8];
            *(float4*)&a[0] = *(const float4*)&As[k][ty * 8];
            *(float4*)&a[4] = *(const float4*)&As[k][ty * 8 + 4];
            *(float4*)&b[0] = *(const float4*)&Bs[k][tx * 8];
            *(float4*)&b[4] = *(const float4*)&Bs[k][tx * 8 + 4];
#pragma unroll
            for (int i = 0; i < 8; i++)
#pragma unroll
                for (int j = 0; j < 8; j++)
                    acc[i][j] = fmaf(a[i], b[j], acc[i][j]);
        }
        __syncthreads();
    }

    float4 bg0 = *(const float4*)&bg[n0 + tx * 8];
    float4 bg1 = *(const float4*)&bg[n0 + tx * 8 + 4];
#pragma unroll
    for (int i = 0; i < 8; i++) {
        const int row = m0 + ty * 8 + i;
        float* orow = &logits[(size_t)row * DDIM + n0 + tx * 8];
        float4 v0, v1;
        v0.x = acc[i][0] + bg0.x; v0.y = acc[i][1] + bg0.y;
        v0.z = acc[i][2] + bg0.z; v0.w = acc[i][3] + bg0.w;
        v1.x = acc[i][4] + bg1.x; v1.y = acc[i][5] + bg1.y;
        v1.z = acc[i][6] + bg1.z; v1.w = acc[i][7] + bg1.w;
        *(float4*)&orow[0] = v0;
        *(float4*)&orow[4] = v1;
    }
}

// ---------------------------------------------------------------------------
// K2: per-row max/argmax (first-occurrence tiebreak, matches numpy),
//     sum of exp(l - max)  ->  p = 1/sum, e = argmax % 8, histogram cnt[e]
// ---------------------------------------------------------------------------
__global__ __launch_bounds__(256) void row_stats(
    const float* __restrict__ logits, float* __restrict__ pout,
    int* __restrict__ eout, int* __restrict__ cnt)
{
    __shared__ float sv[256];
    __shared__ int   si[256];
    const int row = blockIdx.x;
    const int tid = threadIdx.x;
    float4 v = *(const float4*)&logits[(size_t)row * DDIM + tid * 4];
    float m = v.x; int mi = tid * 4;
    if (v.y > m) { m = v.y; mi = tid * 4 + 1; }
    if (v.z > m) { m = v.z; mi = tid * 4 + 2; }
    if (v.w > m) { m = v.w; mi = tid * 4 + 3; }
    sv[tid] = m; si[tid] = mi;
    __syncthreads();
    for (int off = 128; off > 0; off >>= 1) {
        if (tid < off) {
            float ov = sv[tid + off]; int oi = si[tid + off];
            if (ov > sv[tid] || (ov == sv[tid] && oi < si[tid])) {
                sv[tid] = ov; si[tid] = oi;
            }
        }
        __syncthreads();
    }
    const float rmax = sv[0];
    const int   ridx = si[0];
    __syncthreads();
    float s = expf(v.x - rmax) + expf(v.y - rmax) +
              expf(v.z - rmax) + expf(v.w - rmax);
    sv[tid] = s;
    __syncthreads();
    for (int off = 128; off > 0; off >>= 1) {
        if (tid < off) sv[tid] += sv[tid + off];
        __syncthreads();
    }
    if (tid == 0) {
        pout[row] = 1.0f / sv[0];
        int e = ridx & (NEXP - 1);
        eout[row] = e;
        atomicAdd(&cnt[e], 1);
    }
}

// ---------------------------------------------------------------------------
// K3: padded segment starts + row-block -> expert map (single thread, tiny)
// ---------------------------------------------------------------------------
__global__ void compute_offsets(const int* __restrict__ cnt,
                                int* __restrict__ start,
                                int* __restrict__ blk_expert)
{
    if (threadIdx.x == 0 && blockIdx.x == 0) {
        int st[NEXP + 1];
        int total = 0;
        for (int e = 0; e < NEXP; e++) {
            st[e] = total;
            total += ((cnt[e] + BMT - 1) / BMT) * BMT;
        }
        st[NEXP] = total;
        for (int e = 0; e <= NEXP; e++) start[e] = st[e];
        for (int rb = 0; rb < RB_MAX; rb++) {
            int s = rb * BMT;
            int ex = -1;
            for (int e = 0; e < NEXP; e++)
                if (s >= st[e] && s < st[e + 1]) ex = e;
            blk_expert[rb] = ex;
        }
    }
}

// ---------------------------------------------------------------------------
// K4: token -> slot in expert-sorted order (atomic cursor per expert)
// ---------------------------------------------------------------------------
__global__ __launch_bounds__(256) void assign_slots(
    const int* __restrict__ eout, const int* __restrict__ start,
    int* __restrict__ cursor, int* __restrict__ row_of_slot,
    int* __restrict__ slot_of)
{
    int t = blockIdx.x * 256 + threadIdx.x;
    if (t >= TOK) return;
    int e = eout[t];
    int slot = start[e] + atomicAdd(&cursor[e], 1);
    row_of_slot[slot] = t;
    slot_of[t] = slot;
}

// ---------------------------------------------------------------------------
// K5: gather x rows into expert-sorted bf16 buffer
// ---------------------------------------------------------------------------
__global__ __launch_bounds__(256) void gather_x(
    const float* __restrict__ x, const int* __restrict__ slot_of,
    unsigned short* __restrict__ xg)
{
    const int t = blockIdx.x;
    const int slot = slot_of[t];
    const int c = threadIdx.x * 4;
    float4 v = *(const float4*)&x[(size_t)t * DDIM + c];
    ushort4 o;
    o.x = f2bf(v.x); o.y = f2bf(v.y); o.z = f2bf(v.z); o.w = f2bf(v.w);
    *(ushort4*)&xg[(size_t)slot * DDIM + c] = o;
}

// ---------------------------------------------------------------------------
// K7: expert GEMM, bf16 MFMA 16x16x32, 128x128 tile, BK=32.
// global_load_lds 16B staging; XOR-swizzled LDS layout (k-group ^ (row&3))
// so b128 fragment reads land on 4 distinct bank groups.
// Epilogue: relu(acc + be) * p[token], scatter to original token row.
// ---------------------------------------------------------------------------
__global__ __launch_bounds__(256) void expert_gemm(
    const unsigned short* __restrict__ xg, const unsigned short* __restrict__ WeT,
    const float* __restrict__ be, const float* __restrict__ p,
    const int* __restrict__ row_of_slot, const int* __restrict__ blk_expert,
    float* __restrict__ out)
{
    __shared__ unsigned short Asm[128 * 32];
    __shared__ unsigned short Bsm[128 * 32];
    const int rb = blockIdx.x;
    const int nb = blockIdx.y;
    const int e = blk_expert[rb];
    if (e < 0) return;

    const int tid  = threadIdx.x;
    const int lane = tid & 63;
    const int wave = tid >> 6;
    const int q    = lane >> 4;     // 0..3
    const int m16  = lane & 15;
    const int wrow = (wave & 1) * 64;
    const int wcol = (wave >> 1) * 64;
    const int xq   = (q ^ (m16 & 3)) * 8;   // swizzled k-group offset

    const unsigned short* Aglob = xg + (size_t)rb * 128 * DDIM;
    const unsigned short* Bglob = WeT + (size_t)e * DDIM * DDIM + (size_t)nb * 128 * DDIM;

    f32x4 acc[4][4];
#pragma unroll
    for (int i = 0; i < 4; i++)
#pragma unroll
        for (int j = 0; j < 4; j++) acc[i][j] = (f32x4){0.f, 0.f, 0.f, 0.f};

    for (int k0 = 0; k0 < DDIM; k0 += 32) {
#pragma unroll
        for (int i = 0; i < 2; i++) {
            const int idx = tid + i * 256;
            const int r = idx >> 2;                          // tile row 0..127
            const int kk = (((idx & 3) ^ (r & 3))) * 8;      // swizzled src k-group
            gload_lds16(Aglob + (size_t)r * DDIM + k0 + kk, &Asm[idx * 8]);
            gload_lds16(Bglob + (size_t)r * DDIM + k0 + kk, &Bsm[idx * 8]);
        }
        __syncthreads();
        bf16x8 af[4], bfr[4];
#pragma unroll
        for (int i = 0; i < 4; i++)
            af[i] = *(const bf16x8*)&Asm[(wrow + i * 16 + m16) * 32 + xq];
#pragma unroll
        for (int j = 0; j < 4; j++)
            bfr[j] = *(const bf16x8*)&Bsm[(wcol + j * 16 + m16) * 32 + xq];
#pragma unroll
        for (int i = 0; i < 4; i++)
#pragma unroll
            for (int j = 0; j < 4; j++)
                acc[i][j] = __builtin_amdgcn_mfma_f32_16x16x32_bf16(
                    af[i], bfr[j], acc[i][j], 0, 0, 0);
        __syncthreads();
    }

    // C/D layout: col = lane&15, row = (lane>>4)*4 + reg
#pragma unroll
    for (int i = 0; i < 4; i++) {
#pragma unroll
        for (int r = 0; r < 4; r++) {
            const int s = rb * 128 + wrow + i * 16 + q * 4 + r;
            const int t = row_of_slot[s];
            if (t < 0) continue;
            const float pv = p[t];
#pragma unroll
            for (int j = 0; j < 4; j++) {
                const int n = nb * 128 + wcol + j * 16 + m16;
                float v = acc[i][j][r] + be[e * DDIM + n];
                v = v > 0.f ? v : 0.f;
                out[(size_t)t * DDIM + n] = v * pv;
            }
        }
    }
}

// ---------------------------------------------------------------------------
extern "C" void kernel_launch(void* const* d_in, const int* in_sizes, int n_in,
                              void* d_out, int out_size, void* d_ws, size_t ws_size,
                              hipStream_t stream)
{
    const float* x  = (const float*)d_in[0];
    const float* Wg = (const float*)d_in[1];
    const float* bg = (const float*)d_in[2];
    const float* We = (const float*)d_in[3];
    const float* be = (const float*)d_in[4];
    float* out = (float*)d_out;

    char* ws = (char*)d_ws;
    float* logits = (float*)ws;                 ws += (size_t)TOK * DDIM * 4;
    unsigned short* xg = (unsigned short*)ws;   ws += (size_t)RB_MAX * BMT * DDIM * 2;
    unsigned short* WeT = (unsigned short*)ws;  ws += (size_t)NEXP * DDIM * DDIM * 2;
    float* p = (float*)ws;                      ws += (size_t)TOK * 4;
    int* e_arr = (int*)ws;                      ws += (size_t)TOK * 4;
    int* slot_of = (int*)ws;                    ws += (size_t)TOK * 4;
    int* row_of_slot = (int*)ws;                ws += (size_t)RB_MAX * BMT * 4;
    int* cnt = (int*)ws;                        ws += NEXP * 4;
    int* cursor = (int*)ws;                     ws += NEXP * 4;
    int* start = (int*)ws;                      ws += (NEXP + 1) * 4;
    int* blk_expert = (int*)ws;                 ws += RB_MAX * 4;

    hipMemsetAsync(cnt, 0, NEXP * 4, stream);
    hipMemsetAsync(cursor, 0, NEXP * 4, stream);
    hipMemsetAsync(row_of_slot, 0xFF, (size_t)RB_MAX * BMT * 4, stream);
    hipMemsetAsync(xg, 0, (size_t)RB_MAX * BMT * DDIM * 2, stream);

    transpose_we<<<dim3(32, 32, NEXP), dim3(32, 8), 0, stream>>>(We, WeT);
    gating_gemm<<<dim3(TOK / 128, DDIM / 128), 256, 0, stream>>>(x, Wg, bg, logits);
    row_stats<<<TOK, 256, 0, stream>>>(logits, p, e_arr, cnt);
    compute_offsets<<<1, 64, 0, stream>>>(cnt, start, blk_expert);
    assign_slots<<<TOK / 256, 256, 0, stream>>>(e_arr, start, cursor, row_of_slot, slot_of);
    gather_x<<<TOK, 256, 0, stream>>>(x, slot_of, xg);
    expert_gemm<<<dim3(RB_MAX, DDIM / 128), 256, 0, stream>>>(
        xg, WeT, be, p, row_of_slot, blk_expert, out);
}

// Round 2
// 476.731 us; speedup vs baseline: 1.8651x; 1.8651x over previous
//
#include <hip/hip_runtime.h>
#include <stdint.h>
#include <stddef.h>

#define TOK    16384     // B*S
#define DDIM   1024
#define NEXP   8
#define BMT    128       // expert gemm row tile (padding quantum)
#define RB_MAX 136       // ceil((TOK + NEXP*BMT)/BMT) upper bound
#define MARGIN 1e-3f     // split-logit ambiguity margin (~22 sigma of split err)
#define AMBIG_CAP 256

typedef __bf16 bf16x8 __attribute__((ext_vector_type(8)));
typedef float  f32x4  __attribute__((ext_vector_type(4)));
typedef unsigned short u16x8 __attribute__((ext_vector_type(8)));

__device__ __forceinline__ unsigned short f2bf(float f) {
    unsigned int u = __float_as_uint(f);
    u += 0x7fff + ((u >> 16) & 1);          // round-to-nearest-even
    return (unsigned short)(u >> 16);
}
__device__ __forceinline__ float bf2f(unsigned short h) {
    return __uint_as_float((unsigned int)h << 16);
}

__device__ __forceinline__ void gload_lds16(const void* g, void* l) {
    __builtin_amdgcn_global_load_lds(
        (const __attribute__((address_space(1))) unsigned int*)g,
        (__attribute__((address_space(3))) unsigned int*)l, 16, 0, 0);
}

// ---------------------------------------------------------------------------
// Wg[k][n] fp32 -> WgT_hi[n][k], WgT_lo[n][k] bf16 split (B operand k-contig)
// ---------------------------------------------------------------------------
__global__ __launch_bounds__(256) void split_wg(
    const float* __restrict__ Wg,
    unsigned short* __restrict__ Wh, unsigned short* __restrict__ Wl)
{
    __shared__ float tile[32][33];
    const int k0 = blockIdx.x * 32;
    const int n0 = blockIdx.y * 32;
    const int tx = threadIdx.x;   // 0..31
    const int ty = threadIdx.y;   // 0..7
#pragma unroll
    for (int r = 0; r < 4; r++)
        tile[ty + r * 8][tx] = Wg[(size_t)(k0 + ty + r * 8) * DDIM + n0 + tx];
    __syncthreads();
#pragma unroll
    for (int r = 0; r < 4; r++) {
        float v = tile[tx][ty + r * 8];
        unsigned short h = f2bf(v);
        unsigned short l = f2bf(v - bf2f(h));
        size_t o = (size_t)(n0 + ty + r * 8) * DDIM + k0 + tx;
        Wh[o] = h; Wl[o] = l;
    }
}

// ---------------------------------------------------------------------------
// We[e][k][n] fp32 -> WeT[e][n][k] bf16
// ---------------------------------------------------------------------------
__global__ __launch_bounds__(256) void transpose_we(
    const float* __restrict__ We, unsigned short* __restrict__ WeT)
{
    __shared__ float tile[32][33];
    const int e  = blockIdx.z;
    const int k0 = blockIdx.x * 32;
    const int n0 = blockIdx.y * 32;
    const int tx = threadIdx.x;
    const int ty = threadIdx.y;
    const float* src = We + (size_t)e * DDIM * DDIM;
    unsigned short* dst = WeT + (size_t)e * DDIM * DDIM;
#pragma unroll
    for (int r = 0; r < 4; r++)
        tile[ty + r * 8][tx] = src[(size_t)(k0 + ty + r * 8) * DDIM + n0 + tx];
    __syncthreads();
#pragma unroll
    for (int r = 0; r < 4; r++)
        dst[(size_t)(n0 + ty + r * 8) * DDIM + k0 + tx] = f2bf(tile[tx][ty + r * 8]);
}

// ---------------------------------------------------------------------------
// Gating GEMM on matrix cores, double-bf16 split:
// logits = xh@WhT + xh@WlT + xl@WhT  (+bg), fp32 accum.
// A staged manually from fp32 x (hi/lo cvt in regs -> ds_write_b128);
// B (hi,lo) via global_load_lds 16B. 128x128 tile, BK=32, 48 MFMA/K-step.
// ---------------------------------------------------------------------------
__global__ __launch_bounds__(256) void gating_mfma(
    const float* __restrict__ x,
    const unsigned short* __restrict__ WgTh, const unsigned short* __restrict__ WgTl,
    const float* __restrict__ bg, float* __restrict__ logits)
{
    __shared__ unsigned short Ah[128 * 32], Al[128 * 32];
    __shared__ unsigned short Bh[128 * 32], Bl[128 * 32];
    const int rb = blockIdx.x;
    const int nb = blockIdx.y;
    const int tid  = threadIdx.x;
    const int lane = tid & 63;
    const int wave = tid >> 6;
    const int q    = lane >> 4;
    const int m16  = lane & 15;
    const int wrow = (wave & 1) * 64;
    const int wcol = (wave >> 1) * 64;
    const int xq   = (q ^ (m16 & 3)) * 8;

    const float* Ag = x + (size_t)rb * 128 * DDIM;
    const unsigned short* Bhg = WgTh + (size_t)nb * 128 * DDIM;
    const unsigned short* Blg = WgTl + (size_t)nb * 128 * DDIM;

    f32x4 acc[4][4];
#pragma unroll
    for (int i = 0; i < 4; i++)
#pragma unroll
        for (int j = 0; j < 4; j++) acc[i][j] = (f32x4){0.f, 0.f, 0.f, 0.f};

    for (int k0 = 0; k0 < DDIM; k0 += 32) {
#pragma unroll
        for (int i = 0; i < 2; i++) {
            const int idx = tid + i * 256;
            const int r = idx >> 2;
            const int kk = ((idx & 3) ^ (r & 3)) * 8;
            gload_lds16(Bhg + (size_t)r * DDIM + k0 + kk, &Bh[idx * 8]);
            gload_lds16(Blg + (size_t)r * DDIM + k0 + kk, &Bl[idx * 8]);
            float4 v0 = *(const float4*)(Ag + (size_t)r * DDIM + k0 + kk);
            float4 v1 = *(const float4*)(Ag + (size_t)r * DDIM + k0 + kk + 4);
            float vv[8] = {v0.x, v0.y, v0.z, v0.w, v1.x, v1.y, v1.z, v1.w};
            u16x8 hh, ll;
#pragma unroll
            for (int j = 0; j < 8; j++) {
                unsigned short h = f2bf(vv[j]);
                hh[j] = h;
                ll[j] = f2bf(vv[j] - bf2f(h));
            }
            *(u16x8*)&Ah[idx * 8] = hh;
            *(u16x8*)&Al[idx * 8] = ll;
        }
        __syncthreads();
        bf16x8 ah[4], al[4], bhf[4], blf[4];
#pragma unroll
        for (int i = 0; i < 4; i++) {
            ah[i] = *(const bf16x8*)&Ah[(wrow + i * 16 + m16) * 32 + xq];
            al[i] = *(const bf16x8*)&Al[(wrow + i * 16 + m16) * 32 + xq];
        }
#pragma unroll
        for (int j = 0; j < 4; j++) {
            bhf[j] = *(const bf16x8*)&Bh[(wcol + j * 16 + m16) * 32 + xq];
            blf[j] = *(const bf16x8*)&Bl[(wcol + j * 16 + m16) * 32 + xq];
        }
#pragma unroll
        for (int i = 0; i < 4; i++)
#pragma unroll
            for (int j = 0; j < 4; j++) {
                acc[i][j] = __builtin_amdgcn_mfma_f32_16x16x32_bf16(ah[i], bhf[j], acc[i][j], 0, 0, 0);
                acc[i][j] = __builtin_amdgcn_mfma_f32_16x16x32_bf16(ah[i], blf[j], acc[i][j], 0, 0, 0);
                acc[i][j] = __builtin_amdgcn_mfma_f32_16x16x32_bf16(al[i], bhf[j], acc[i][j], 0, 0, 0);
            }
        __syncthreads();
    }

    float bgv[4];
#pragma unroll
    for (int j = 0; j < 4; j++) bgv[j] = bg[nb * 128 + wcol + j * 16 + m16];
#pragma unroll
    for (int i = 0; i < 4; i++)
#pragma unroll
        for (int r = 0; r < 4; r++) {
            const int row = rb * 128 + wrow + i * 16 + q * 4 + r;
#pragma unroll
            for (int j = 0; j < 4; j++) {
                const int col = nb * 128 + wcol + j * 16 + m16;
                logits[(size_t)row * DDIM + col] = acc[i][j][r] + bgv[j];
            }
        }
}

// ---------------------------------------------------------------------------
// Row stats: one wave per row. top-1 (val,idx) with numpy first-occurrence
// tiebreak, sumexp, ambiguity detection (2nd candidate within MARGIN).
// ---------------------------------------------------------------------------
__global__ __launch_bounds__(256) void row_stats(
    const float* __restrict__ logits, float* __restrict__ pout,
    int* __restrict__ eout, float* __restrict__ rmax_a, float* __restrict__ s_a,
    int* __restrict__ ambig, int* __restrict__ n_ambig)
{
    const int row  = blockIdx.x * 4 + (threadIdx.x >> 6);
    const int lane = threadIdx.x & 63;
    const float* L = logits + (size_t)row * DDIM;
    float vals[16];
#pragma unroll
    for (int i = 0; i < 4; i++)
        *(float4*)&vals[i * 4] = *(const float4*)&L[lane * 16 + i * 4];
    float m = vals[0]; int mi = lane * 16;
#pragma unroll
    for (int i = 1; i < 16; i++)
        if (vals[i] > m) { m = vals[i]; mi = lane * 16 + i; }
    for (int off = 32; off > 0; off >>= 1) {
        float ov = __shfl_down(m, off, 64);
        int   oi = __shfl_down(mi, off, 64);
        if (ov > m || (ov == m && oi < mi)) { m = ov; mi = oi; }
    }
    m  = __shfl(m, 0, 64);
    mi = __shfl(mi, 0, 64);
    float s = 0.f;
    int   c = 0;
#pragma unroll
    for (int i = 0; i < 16; i++) {
        s += __expf(vals[i] - m) * 0.f + expf(vals[i] - m);
        if (vals[i] >= m - MARGIN) c++;
    }
    for (int off = 32; off > 0; off >>= 1) {
        s += __shfl_xor(s, off, 64);
        c += __shfl_xor(c, off, 64);
    }
    if (lane == 0) {
        pout[row] = 1.0f / s;
        eout[row] = mi & (NEXP - 1);
        rmax_a[row] = m;
        s_a[row] = s;
        if (c > 1) {
            int k = atomicAdd(n_ambig, 1);
            if (k < AMBIG_CAP) ambig[k] = row;
        }
    }
}

// ---------------------------------------------------------------------------
// Fix-up: for ambiguous rows, fp64 re-score candidate columns from the
// ORIGINAL fp32 x, Wg; commit exact argmax (numpy tiebreak: lower idx).
// ---------------------------------------------------------------------------
__global__ __launch_bounds__(64) void fixup(
    const float* __restrict__ logits, const float* __restrict__ x,
    const float* __restrict__ Wg, const float* __restrict__ bg,
    const float* __restrict__ rmax_a, const float* __restrict__ s_a,
    const int* __restrict__ ambig, const int* __restrict__ n_ambig,
    int* __restrict__ eout, float* __restrict__ pout)
{
    int n = *n_ambig; if (n > AMBIG_CAP) n = AMBIG_CAP;
    if ((int)blockIdx.x >= n) return;
    const int row  = ambig[blockIdx.x];
    const int lane = threadIdx.x;
    const float rmax = rmax_a[row];
    const float* L = logits + (size_t)row * DDIM;
    __shared__ int scnt;
    __shared__ int scol[32];
    if (lane == 0) scnt = 0;
    __syncthreads();
    for (int j = lane; j < DDIM; j += 64)
        if (L[j] >= rmax - MARGIN) {
            int k = atomicAdd(&scnt, 1);
            if (k < 32) scol[k] = j;
        }
    __syncthreads();
    int ncand = scnt < 32 ? scnt : 32;
    double bestv = -1e300; int bestc = DDIM;
    for (int cidx = 0; cidx < ncand; cidx++) {
        const int col = scol[cidx];
        double s = 0.0;
        for (int k = lane; k < DDIM; k += 64)
            s += (double)x[(size_t)row * DDIM + k] * (double)Wg[(size_t)k * DDIM + col];
        for (int off = 32; off > 0; off >>= 1) s += __shfl_down(s, off, 64);
        s = __shfl(s, 0, 64);
        s += (double)bg[col];
        if (s > bestv || (s == bestv && col < bestc)) { bestv = s; bestc = col; }
    }
    if (lane == 0) {
        eout[row] = bestc & (NEXP - 1);
        pout[row] = expf(L[bestc] - rmax) / s_a[row];
    }
}

// ---------------------------------------------------------------------------
// Expert histogram (after fixup so counts are final)
// ---------------------------------------------------------------------------
__global__ __launch_bounds__(256) void histo(const int* __restrict__ eout,
                                             int* __restrict__ cnt)
{
    __shared__ int h[NEXP];
    if (threadIdx.x < NEXP) h[threadIdx.x] = 0;
    __syncthreads();
    const int t = blockIdx.x * 256 + threadIdx.x;
    if (t < TOK) atomicAdd(&h[eout[t]], 1);
    __syncthreads();
    if (threadIdx.x < NEXP) atomicAdd(&cnt[threadIdx.x], h[threadIdx.x]);
}

// ---------------------------------------------------------------------------
// Padded segment starts + row-block -> expert map (single thread, tiny)
// ---------------------------------------------------------------------------
__global__ void compute_offsets(const int* __restrict__ cnt,
                                int* __restrict__ start,
                                int* __restrict__ blk_expert)
{
    if (threadIdx.x == 0 && blockIdx.x == 0) {
        int st[NEXP + 1];
        int total = 0;
        for (int e = 0; e < NEXP; e++) {
            st[e] = total;
            total += ((cnt[e] + BMT - 1) / BMT) * BMT;
        }
        st[NEXP] = total;
        for (int e = 0; e <= NEXP; e++) start[e] = st[e];
        for (int rb = 0; rb < RB_MAX; rb++) {
            int s = rb * BMT;
            int ex = -1;
            for (int e = 0; e < NEXP; e++)
                if (s >= st[e] && s < st[e + 1]) ex = e;
            blk_expert[rb] = ex;
        }
    }
}

// ---------------------------------------------------------------------------
// token -> slot (atomic cursor per expert)
// ---------------------------------------------------------------------------
__global__ __launch_bounds__(256) void assign_slots(
    const int* __restrict__ eout, const int* __restrict__ start,
    int* __restrict__ cursor, int* __restrict__ row_of_slot)
{
    int t = blockIdx.x * 256 + threadIdx.x;
    if (t >= TOK) return;
    int e = eout[t];
    int slot = start[e] + atomicAdd(&cursor[e], 1);
    row_of_slot[slot] = t;
}

// ---------------------------------------------------------------------------
// Expert GEMM: A gathered indirectly from fp32 x via row_of_slot (cvt to
// bf16 in regs -> ds_write_b128); B = WeT via global_load_lds. bf16 MFMA
// 16x16x32, 128x128 tile, BK=32. Epilogue: relu(acc+be)*p -> scatter.
// ---------------------------------------------------------------------------
__global__ __launch_bounds__(256) void expert_gemm(
    const float* __restrict__ x, const unsigned short* __restrict__ WeT,
    const float* __restrict__ be, const float* __restrict__ p,
    const int* __restrict__ row_of_slot, const int* __restrict__ blk_expert,
    float* __restrict__ out)
{
    __shared__ unsigned short Asm[128 * 32];
    __shared__ unsigned short Bsm[128 * 32];
    __shared__ int rs[128];
    const int rb = blockIdx.x;
    const int nb = blockIdx.y;
    const int e = blk_expert[rb];
    if (e < 0) return;

    const int tid  = threadIdx.x;
    const int lane = tid & 63;
    const int wave = tid >> 6;
    const int q    = lane >> 4;
    const int m16  = lane & 15;
    const int wrow = (wave & 1) * 64;
    const int wcol = (wave >> 1) * 64;
    const int xq   = (q ^ (m16 & 3)) * 8;

    if (tid < 128) rs[tid] = row_of_slot[rb * 128 + tid];
    __syncthreads();

    const unsigned short* Bglob = WeT + (size_t)e * DDIM * DDIM + (size_t)nb * 128 * DDIM;

    f32x4 acc[4][4];
#pragma unroll
    for (int i = 0; i < 4; i++)
#pragma unroll
        for (int j = 0; j < 4; j++) acc[i][j] = (f32x4){0.f, 0.f, 0.f, 0.f};

    for (int k0 = 0; k0 < DDIM; k0 += 32) {
#pragma unroll
        for (int i = 0; i < 2; i++) {
            const int idx = tid + i * 256;
            const int r = idx >> 2;
            const int kk = ((idx & 3) ^ (r & 3)) * 8;
            gload_lds16(Bglob + (size_t)r * DDIM + k0 + kk, &Bsm[idx * 8]);
            int trow = rs[r];
            int srow = trow < 0 ? 0 : trow;   // pad rows: load row 0, discard later
            const float* src = x + (size_t)srow * DDIM + k0 + kk;
            float4 v0 = *(const float4*)src;
            float4 v1 = *(const float4*)(src + 4);
            float vv[8] = {v0.x, v0.y, v0.z, v0.w, v1.x, v1.y, v1.z, v1.w};
            u16x8 hh;
#pragma unroll
            for (int j = 0; j < 8; j++) hh[j] = f2bf(vv[j]);
            *(u16x8*)&Asm[idx * 8] = hh;
        }
        __syncthreads();
        bf16x8 af[4], bfr[4];
#pragma unroll
        for (int i = 0; i < 4; i++)
            af[i] = *(const bf16x8*)&Asm[(wrow + i * 16 + m16) * 32 + xq];
#pragma unroll
        for (int j = 0; j < 4; j++)
            bfr[j] = *(const bf16x8*)&Bsm[(wcol + j * 16 + m16) * 32 + xq];
#pragma unroll
        for (int i = 0; i < 4; i++)
#pragma unroll
            for (int j = 0; j < 4; j++)
                acc[i][j] = __builtin_amdgcn_mfma_f32_16x16x32_bf16(
                    af[i], bfr[j], acc[i][j], 0, 0, 0);
        __syncthreads();
    }

    float bev[4];
#pragma unroll
    for (int j = 0; j < 4; j++) bev[j] = be[e * DDIM + nb * 128 + wcol + j * 16 + m16];
#pragma unroll
    for (int i = 0; i < 4; i++)
#pragma unroll
        for (int r = 0; r < 4; r++) {
            const int t = rs[wrow + i * 16 + q * 4 + r];
            if (t < 0) continue;
            const float pv = p[t];
#pragma unroll
            for (int j = 0; j < 4; j++) {
                const int n = nb * 128 + wcol + j * 16 + m16;
                float v = acc[i][j][r] + bev[j];
                v = v > 0.f ? v : 0.f;
                out[(size_t)t * DDIM + n] = v * pv;
            }
        }
}

// ---------------------------------------------------------------------------
extern "C" void kernel_launch(void* const* d_in, const int* in_sizes, int n_in,
                              void* d_out, int out_size, void* d_ws, size_t ws_size,
                              hipStream_t stream)
{
    const float* x  = (const float*)d_in[0];
    const float* Wg = (const float*)d_in[1];
    const float* bg = (const float*)d_in[2];
    const float* We = (const float*)d_in[3];
    const float* be = (const float*)d_in[4];
    float* out = (float*)d_out;

    char* ws = (char*)d_ws;
    float* logits = (float*)ws;                 ws += (size_t)TOK * DDIM * 4;
    unsigned short* WeT = (unsigned short*)ws;  ws += (size_t)NEXP * DDIM * DDIM * 2;
    unsigned short* WgTh = (unsigned short*)ws; ws += (size_t)DDIM * DDIM * 2;
    unsigned short* WgTl = (unsigned short*)ws; ws += (size_t)DDIM * DDIM * 2;
    float* p = (float*)ws;                      ws += (size_t)TOK * 4;
    int* e_arr = (int*)ws;                      ws += (size_t)TOK * 4;
    float* rmax_a = (float*)ws;                 ws += (size_t)TOK * 4;
    float* s_a = (float*)ws;                    ws += (size_t)TOK * 4;
    int* row_of_slot = (int*)ws;                ws += (size_t)RB_MAX * BMT * 4;
    int* cnt = (int*)ws;                        ws += NEXP * 4;
    int* cursor = (int*)ws;                     ws += NEXP * 4;
    int* start = (int*)ws;                      ws += (NEXP + 1) * 4;
    int* blk_expert = (int*)ws;                 ws += RB_MAX * 4;
    int* ambig = (int*)ws;                      ws += AMBIG_CAP * 4;
    int* n_ambig = (int*)ws;                    ws += 4;

    hipMemsetAsync(cnt, 0, NEXP * 4, stream);
    hipMemsetAsync(cursor, 0, NEXP * 4, stream);
    hipMemsetAsync(n_ambig, 0, 4, stream);
    hipMemsetAsync(row_of_slot, 0xFF, (size_t)RB_MAX * BMT * 4, stream);

    split_wg<<<dim3(32, 32), dim3(32, 8), 0, stream>>>(Wg, WgTh, WgTl);
    transpose_we<<<dim3(32, 32, NEXP), dim3(32, 8), 0, stream>>>(We, WeT);
    gating_mfma<<<dim3(TOK / 128, DDIM / 128), 256, 0, stream>>>(x, WgTh, WgTl, bg, logits);
    row_stats<<<TOK / 4, 256, 0, stream>>>(logits, p, e_arr, rmax_a, s_a, ambig, n_ambig);
    fixup<<<AMBIG_CAP, 64, 0, stream>>>(logits, x, Wg, bg, rmax_a, s_a, ambig, n_ambig, e_arr, p);
    histo<<<TOK / 256, 256, 0, stream>>>(e_arr, cnt);
    compute_offsets<<<1, 64, 0, stream>>>(cnt, start, blk_expert);
    assign_slots<<<TOK / 256, 256, 0, stream>>>(e_arr, start, cursor, row_of_slot);
    expert_gemm<<<dim3(RB_MAX, DDIM / 128), 256, 0, stream>>>(
        x, WeT, be, p, row_of_slot, blk_expert, out);
}